// Round 1
// baseline (792.240 us; speedup 1.0000x reference)
//
#include <hip/hip_runtime.h>

typedef unsigned short u16;
typedef __attribute__((ext_vector_type(8))) short bf16x8;
typedef __attribute__((ext_vector_type(4))) float f32x4;

__device__ __forceinline__ u16 f2bf(float x) {
  unsigned u = __float_as_uint(x);
  u += 0x7fffu + ((u >> 16) & 1u);   // RNE
  return (u16)(u >> 16);
}

// ---------------- cast fp32 -> bf16 (RNE); n divisible by 1024 ----------------
__global__ __launch_bounds__(256) void cast_kernel(const float* __restrict__ in,
                                                   u16* __restrict__ out, int n) {
  int i = (blockIdx.x * 256 + threadIdx.x) * 4;
  if (i >= n) return;
  float4 f = *(const float4*)(in + i);
  ushort4 o;
  o.x = f2bf(f.x); o.y = f2bf(f.y); o.z = f2bf(f.z); o.w = f2bf(f.w);
  *(ushort4*)(out + i) = o;
}

// ------------- transpose+cast 4 weights: W[k][n] fp32 -> Wt[n][k] bf16 -------------
__global__ __launch_bounds__(256) void transcast(const float* __restrict__ W0,
                                                 const float* __restrict__ W1,
                                                 const float* __restrict__ W2,
                                                 const float* __restrict__ W3,
                                                 u16* __restrict__ out) {
  __shared__ alignas(16) u16 ls[64 * 72];
  int z = blockIdx.z;
  const float* W = (z == 0) ? W0 : (z == 1) ? W1 : (z == 2) ? W2 : W3;
  u16* o = out + (size_t)z * (1024u * 1024u);
  int kt = blockIdx.y * 64, nt = blockIdx.x * 64;
  int tid = threadIdx.x;
  int r = tid >> 2, c0 = (tid & 3) * 16;
  const float* src = W + (size_t)(kt + r) * 1024 + nt + c0;
  u16 tmp[16];
#pragma unroll
  for (int c = 0; c < 16; c += 4) {
    float4 f = *(const float4*)(src + c);
    tmp[c + 0] = f2bf(f.x); tmp[c + 1] = f2bf(f.y);
    tmp[c + 2] = f2bf(f.z); tmp[c + 3] = f2bf(f.w);
  }
#pragma unroll
  for (int c = 0; c < 16; ++c) ls[r * 72 + c0 + c] = tmp[c];
  __syncthreads();
#pragma unroll
  for (int pass = 0; pass < 4; ++pass) {
    int n = pass * 16 + (tid >> 4);
    int kk = (tid & 15) * 4;
    ushort4 val;
    val.x = ls[(kk + 0) * 72 + n];
    val.y = ls[(kk + 1) * 72 + n];
    val.z = ls[(kk + 2) * 72 + n];
    val.w = ls[(kk + 3) * 72 + n];
    *(ushort4*)(o + (size_t)(nt + n) * 1024 + kt + kk) = val;
  }
}

// ------------- bf16 MFMA GEMM: C[M][N] = A[M][K] * B[N][K]^T, fp32 out -------------
#define BM 128
#define BN 64
#define BK 32
#define LDA 48  // padded LDS stride (96B): bank-balanced b128 frag reads

__global__ __launch_bounds__(256) void gemm_bf16(const u16* __restrict__ A,
                                                 const u16* __restrict__ Bmat,
                                                 float* __restrict__ C,
                                                 int K, int N, size_t bz, size_t cz) {
  __shared__ alignas(16) u16 As[BM * LDA];
  __shared__ alignas(16) u16 Bs[BN * LDA];
  const u16* B = Bmat + (size_t)blockIdx.z * bz;
  float* Cz = C + (size_t)blockIdx.z * cz;
  int tid = threadIdx.x;
  int bm = blockIdx.y * BM, bn = blockIdx.x * BN;
  int lane = tid & 63, w = tid >> 6;
  int wm = (w >> 1) * 64, wn = (w & 1) * 32;
  int m16 = lane & 15, q = lane >> 4;
  f32x4 acc[4][2] = {};
  int arow = tid >> 1, acol = (tid & 1) * 16;
  int brow = tid >> 2, bcol = (tid & 3) * 8;
  const u16* aptr = A + (size_t)(bm + arow) * K + acol;
  const u16* bptr = B + (size_t)(bn + brow) * K + bcol;
  for (int k0 = 0; k0 < K; k0 += BK) {
    uint4 a0 = *(const uint4*)(aptr + k0);
    uint4 a1 = *(const uint4*)(aptr + k0 + 8);
    uint4 b0 = *(const uint4*)(bptr + k0);
    __syncthreads();
    *(uint4*)&As[arow * LDA + acol] = a0;
    *(uint4*)&As[arow * LDA + acol + 8] = a1;
    *(uint4*)&Bs[brow * LDA + bcol] = b0;
    __syncthreads();
    bf16x8 af[4], bfr[2];
#pragma unroll
    for (int mt = 0; mt < 4; ++mt)
      af[mt] = *(const bf16x8*)&As[(wm + mt * 16 + m16) * LDA + q * 8];
#pragma unroll
    for (int nt = 0; nt < 2; ++nt)
      bfr[nt] = *(const bf16x8*)&Bs[(wn + nt * 16 + m16) * LDA + q * 8];
#pragma unroll
    for (int mt = 0; mt < 4; ++mt)
#pragma unroll
      for (int nt = 0; nt < 2; ++nt)
        acc[mt][nt] = __builtin_amdgcn_mfma_f32_16x16x32_bf16(af[mt], bfr[nt], acc[mt][nt], 0, 0, 0);
  }
#pragma unroll
  for (int mt = 0; mt < 4; ++mt)
#pragma unroll
    for (int nt = 0; nt < 2; ++nt)
#pragma unroll
      for (int r = 0; r < 4; ++r) {
        int row = bm + wm + mt * 16 + q * 4 + r;
        int col = bn + wn + nt * 16 + m16;
        Cz[(size_t)row * N + col] = acc[mt][nt][r];
      }
}

// ------------- cosine-norm * s_eff + rotary, in place on q and k -------------
__global__ __launch_bounds__(64) void normrope(float* __restrict__ qbuf,
                                               float* __restrict__ kbuf,
                                               const float* __restrict__ s_qk) {
  int lane = threadIdx.x;
  int idx = blockIdx.x;              // t*16 + h
  float* buf = blockIdx.y ? kbuf : qbuf;
  int t = idx >> 4, h = idx & 15;
  float* p = buf + (size_t)t * 1024 + h * 64;
  float x = p[lane];
  float ss = x * x;
#pragma unroll
  for (int m = 32; m; m >>= 1) ss += __shfl_xor(ss, m);
  float xn = x * rsqrtf(ss + 1e-12f) * (s_qk[h * 64 + lane] * 32.0f);  // sqrt(1024)=32
  float other = __shfl_xor(xn, 32);
  int i = lane & 31;
  float fr = (i < 16) ? exp2f(-10.0f * (float)i / 15.0f) : 0.0f;  // (1/1024)^(i/15)
  float th = (float)t * fr;
  float c = cosf(th), s = sinf(th);
  float sgn = (lane < 32) ? s : -s;  // y1 = x1*c + x2*s ; y2 = x2*c - x1*s
  p[lane] = xn * c + other * sgn;
}

// ------------- causal attention, fp32 vector; no max-subtraction (|score|<=0.27) ---
#define RROWS 16
__global__ __launch_bounds__(64) void attn_kernel(const float* __restrict__ q,
                                                  const float* __restrict__ k,
                                                  const float* __restrict__ v,
                                                  u16* __restrict__ yb) {
  int lane = threadIdx.x;
  int h = blockIdx.x;
  int t0 = blockIdx.y * RROWS;
  const float* qb = q + (size_t)t0 * 1024 + h * 64;
  const float* kb = k + h * 64;
  const float* vb = v + h * 64 + lane;
  float y[RROWS], lsum[RROWS];
#pragma unroll
  for (int r = 0; r < RROWS; ++r) { y[r] = 0.f; lsum[r] = 0.f; }
  int ntiles = (t0 + RROWS - 1) / 64 + 1;
  for (int jt = 0; jt < ntiles; ++jt) {
    int j = jt * 64 + lane;   // this lane's key index
    const float* krow = kb + (size_t)j * 1024;
    float s[RROWS];
#pragma unroll
    for (int r = 0; r < RROWS; ++r) s[r] = 0.f;
#pragma unroll
    for (int d4 = 0; d4 < 16; ++d4) {
      float4 kv = *(const float4*)(krow + d4 * 4);
#pragma unroll
      for (int r = 0; r < RROWS; ++r) {
        float4 qv = *(const float4*)(qb + (size_t)r * 1024 + d4 * 4);  // uniform -> s_load
        s[r] += kv.x * qv.x + kv.y * qv.y + kv.z * qv.z + kv.w * qv.w;
      }
    }
#pragma unroll
    for (int r = 0; r < RROWS; ++r) {
      float p = (j <= t0 + r) ? __expf(s[r] * 0.12f) : 0.0f;
      s[r] = p;
      lsum[r] += p;
    }
    const float* vrow = vb + (size_t)jt * 64 * 1024;
    for (int jj = 0; jj < 64; jj += 4) {
      float vv0 = vrow[(size_t)(jj + 0) * 1024];
      float vv1 = vrow[(size_t)(jj + 1) * 1024];
      float vv2 = vrow[(size_t)(jj + 2) * 1024];
      float vv3 = vrow[(size_t)(jj + 3) * 1024];
#pragma unroll
      for (int r = 0; r < RROWS; ++r) {
        y[r] += __uint_as_float(__builtin_amdgcn_readlane(__float_as_uint(s[r]), jj + 0)) * vv0;
        y[r] += __uint_as_float(__builtin_amdgcn_readlane(__float_as_uint(s[r]), jj + 1)) * vv1;
        y[r] += __uint_as_float(__builtin_amdgcn_readlane(__float_as_uint(s[r]), jj + 2)) * vv2;
        y[r] += __uint_as_float(__builtin_amdgcn_readlane(__float_as_uint(s[r]), jj + 3)) * vv3;
      }
    }
  }
#pragma unroll
  for (int r = 0; r < RROWS; ++r) {
    float tot = lsum[r];
#pragma unroll
    for (int m = 32; m; m >>= 1) tot += __shfl_xor(tot, m);
    yb[(size_t)(t0 + r) * 1024 + h * 64 + lane] = f2bf(y[r] / tot);
  }
}

extern "C" void kernel_launch(void* const* d_in, const int* in_sizes, int n_in,
                              void* d_out, int out_size, void* d_ws, size_t ws_size,
                              hipStream_t stream) {
  const float* x   = (const float*)d_in[0];
  const float* Wq  = (const float*)d_in[1];
  const float* Wk  = (const float*)d_in[2];
  const float* Wv  = (const float*)d_in[3];
  const float* Wo  = (const float*)d_in[4];
  const float* sqk = (const float*)d_in[5];
  float* out = (float*)d_out;
  char* ws = (char*)d_ws;

  // workspace layout (40 MB total)
  u16*   xb  = (u16*)ws;                       // 4 MB  : x cast to bf16 [2048][1024]
  u16*   Wt  = (u16*)(ws + ((size_t)4 << 20)); // 8 MB  : 4x [n][k] bf16 (q,k,v,o)
  float* qkv = (float*)(ws + ((size_t)12 << 20)); // 24 MB : q,k,v fp32 [2048][1024] each
  u16*   yb  = (u16*)(ws + ((size_t)36 << 20)); // 4 MB  : attention out bf16
  float* qn = qkv;
  float* kn = qkv + (size_t)2048 * 1024;
  float* vv = qkv + (size_t)2 * 2048 * 1024;

  cast_kernel<<<2048, 256, 0, stream>>>(x, xb, 2048 * 1024);
  transcast<<<dim3(16, 16, 4), 256, 0, stream>>>(Wq, Wk, Wv, Wo, Wt);
  gemm_bf16<<<dim3(1024 / BN, 2048 / BM, 3), 256, 0, stream>>>(
      xb, Wt, qkv, 1024, 1024, (size_t)1024 * 1024, (size_t)2048 * 1024);
  normrope<<<dim3(2048 * 16, 2), 64, 0, stream>>>(qn, kn, sqk);
  attn_kernel<<<dim3(16, 2048 / RROWS), 64, 0, stream>>>(qn, kn, vv, yb);
  gemm_bf16<<<dim3(1024 / BN, 2048 / BM, 1), 256, 0, stream>>>(
      yb, Wt + (size_t)3 * 1024 * 1024, out, 1024, 1024, 0, 0);
}

// Round 2
// 201.339 us; speedup vs baseline: 3.9349x; 3.9349x over previous
//
#include <hip/hip_runtime.h>

typedef unsigned short u16;
typedef __attribute__((ext_vector_type(8))) short bf16x8;
typedef __attribute__((ext_vector_type(4))) float f32x4;

__device__ __forceinline__ u16 f2bf(float x) {
  unsigned u = __float_as_uint(x);
  u += 0x7fffu + ((u >> 16) & 1u);   // RNE
  return (u16)(u >> 16);
}

// ---------------- cast fp32 -> bf16 (RNE); n divisible by 1024 ----------------
__global__ __launch_bounds__(256) void cast_kernel(const float* __restrict__ in,
                                                   u16* __restrict__ out, int n) {
  int i = (blockIdx.x * 256 + threadIdx.x) * 4;
  if (i >= n) return;
  float4 f = *(const float4*)(in + i);
  ushort4 o;
  o.x = f2bf(f.x); o.y = f2bf(f.y); o.z = f2bf(f.z); o.w = f2bf(f.w);
  *(ushort4*)(out + i) = o;
}

// ------------- transpose+cast 4 weights: W[k][n] fp32 -> Wt[n][k] bf16 -------------
__global__ __launch_bounds__(256) void transcast(const float* __restrict__ W0,
                                                 const float* __restrict__ W1,
                                                 const float* __restrict__ W2,
                                                 const float* __restrict__ W3,
                                                 u16* __restrict__ out) {
  __shared__ alignas(16) u16 ls[64 * 72];
  int z = blockIdx.z;
  const float* W = (z == 0) ? W0 : (z == 1) ? W1 : (z == 2) ? W2 : W3;
  u16* o = out + (size_t)z * (1024u * 1024u);
  int kt = blockIdx.y * 64, nt = blockIdx.x * 64;
  int tid = threadIdx.x;
  int r = tid >> 2, c0 = (tid & 3) * 16;
  const float* src = W + (size_t)(kt + r) * 1024 + nt + c0;
  u16 tmp[16];
#pragma unroll
  for (int c = 0; c < 16; c += 4) {
    float4 f = *(const float4*)(src + c);
    tmp[c + 0] = f2bf(f.x); tmp[c + 1] = f2bf(f.y);
    tmp[c + 2] = f2bf(f.z); tmp[c + 3] = f2bf(f.w);
  }
#pragma unroll
  for (int c = 0; c < 16; ++c) ls[r * 72 + c0 + c] = tmp[c];
  __syncthreads();
#pragma unroll
  for (int pass = 0; pass < 4; ++pass) {
    int n = pass * 16 + (tid >> 4);
    int kk = (tid & 15) * 4;
    ushort4 val;
    val.x = ls[(kk + 0) * 72 + n];
    val.y = ls[(kk + 1) * 72 + n];
    val.z = ls[(kk + 2) * 72 + n];
    val.w = ls[(kk + 3) * 72 + n];
    *(ushort4*)(o + (size_t)(nt + n) * 1024 + kt + kk) = val;
  }
}

// ------------- bf16 MFMA GEMM: C[M][N] = A[M][K] * B[N][K]^T, fp32 out -------------
#define BM 128
#define BN 64
#define BK 32
#define LDA 48  // padded LDS stride (96B): bank-balanced b128 frag reads

__global__ __launch_bounds__(256) void gemm_bf16(const u16* __restrict__ A,
                                                 const u16* __restrict__ Bmat,
                                                 float* __restrict__ C,
                                                 int K, int N, size_t bz, size_t cz) {
  __shared__ alignas(16) u16 As[BM * LDA];
  __shared__ alignas(16) u16 Bs[BN * LDA];
  const u16* B = Bmat + (size_t)blockIdx.z * bz;
  float* Cz = C + (size_t)blockIdx.z * cz;
  int tid = threadIdx.x;
  int bm = blockIdx.y * BM, bn = blockIdx.x * BN;
  int lane = tid & 63, w = tid >> 6;
  int wm = (w >> 1) * 64, wn = (w & 1) * 32;
  int m16 = lane & 15, q = lane >> 4;
  f32x4 acc[4][2] = {};
  int arow = tid >> 1, acol = (tid & 1) * 16;
  int brow = tid >> 2, bcol = (tid & 3) * 8;
  const u16* aptr = A + (size_t)(bm + arow) * K + acol;
  const u16* bptr = B + (size_t)(bn + brow) * K + bcol;
  for (int k0 = 0; k0 < K; k0 += BK) {
    uint4 a0 = *(const uint4*)(aptr + k0);
    uint4 a1 = *(const uint4*)(aptr + k0 + 8);
    uint4 b0 = *(const uint4*)(bptr + k0);
    __syncthreads();
    *(uint4*)&As[arow * LDA + acol] = a0;
    *(uint4*)&As[arow * LDA + acol + 8] = a1;
    *(uint4*)&Bs[brow * LDA + bcol] = b0;
    __syncthreads();
    bf16x8 af[4], bfr[2];
#pragma unroll
    for (int mt = 0; mt < 4; ++mt)
      af[mt] = *(const bf16x8*)&As[(wm + mt * 16 + m16) * LDA + q * 8];
#pragma unroll
    for (int nt = 0; nt < 2; ++nt)
      bfr[nt] = *(const bf16x8*)&Bs[(wn + nt * 16 + m16) * LDA + q * 8];
#pragma unroll
    for (int mt = 0; mt < 4; ++mt)
#pragma unroll
      for (int nt = 0; nt < 2; ++nt)
        acc[mt][nt] = __builtin_amdgcn_mfma_f32_16x16x32_bf16(af[mt], bfr[nt], acc[mt][nt], 0, 0, 0);
  }
#pragma unroll
  for (int mt = 0; mt < 4; ++mt)
#pragma unroll
    for (int nt = 0; nt < 2; ++nt)
#pragma unroll
      for (int r = 0; r < 4; ++r) {
        int row = bm + wm + mt * 16 + q * 4 + r;
        int col = bn + wn + nt * 16 + m16;
        Cz[(size_t)row * N + col] = acc[mt][nt][r];
      }
}

// ------- cosine-norm * s_eff + rotary: read fp32 src, write bf16 dst -------
__global__ __launch_bounds__(256) void normrope(const float* __restrict__ src,
                                                u16* __restrict__ dst,
                                                const float* __restrict__ s_qk) {
  int tid = threadIdx.x;
  int lane = tid & 63;
  int idx = blockIdx.x * 4 + (tid >> 6);   // t*16 + h
  int t = idx >> 4, h = idx & 15;
  const float* p = src + (size_t)t * 1024 + h * 64;
  float x = p[lane];
  float ss = x * x;
#pragma unroll
  for (int m = 32; m; m >>= 1) ss += __shfl_xor(ss, m);
  float xn = x * rsqrtf(ss + 1e-12f) * (s_qk[h * 64 + lane] * 32.0f);  // sqrt(1024)=32
  float other = __shfl_xor(xn, 32);
  int i = lane & 31;
  float fr = (i < 16) ? exp2f(-10.0f * (float)i / 15.0f) : 0.0f;  // (1/1024)^(i/15)
  float th = (float)t * fr;
  float c = cosf(th), s = sinf(th);
  float sgn = (lane < 32) ? s : -s;  // y1 = x1*c + x2*s ; y2 = x2*c - x1*s
  dst[(size_t)t * 1024 + h * 64 + lane] = f2bf(xn * c + other * sgn);
}

// ------------- MFMA flash attention (no-rescale softmax: |score| <= 0.27) ----------
// block = 256 thr (4 waves); 1 head x 64 q-rows per block; wave w handles 16 rows.
#define ALD 72   // LDS stride (144B): b128 frag reads land 2-way on banks (free)
__global__ __launch_bounds__(256) void attn_mfma(const u16* __restrict__ qb,
                                                 const u16* __restrict__ kb,
                                                 const u16* __restrict__ vb,
                                                 u16* __restrict__ yb) {
  __shared__ alignas(16) u16 Ks[64 * ALD];        // K tile [key][d]
  __shared__ alignas(16) u16 Vt[64 * ALD];        // V tile transposed [d][key]
  __shared__ alignas(16) u16 Ps[4 * 16 * ALD];    // per-wave P [row][key]
  int h = blockIdx.x;
  int qt = 31 - blockIdx.y;            // heavy q-tiles dispatch first
  int t0 = qt * 64;
  int tid = threadIdx.x;
  int lane = tid & 63, w = tid >> 6;
  int m16 = lane & 15, q = lane >> 4;
  // Q A-frags for this wave's 16 rows (already normed+roped, bf16)
  const u16* qrow = qb + (size_t)(t0 + w * 16 + m16) * 1024 + h * 64;
  bf16x8 qa0 = *(const bf16x8*)(qrow + q * 8);
  bf16x8 qa1 = *(const bf16x8*)(qrow + 32 + q * 8);
  f32x4 Yacc[4] = {};
  float lsum[4] = {0.f, 0.f, 0.f, 0.f};
  int trow = t0 + w * 16 + q * 4;      // row of acc reg r is trow + r
  int krow_s = tid >> 2, kcol_s = (tid & 3) * 16;  // K staging: 4 thr/row
  int vkey = lane, vd0 = w * 16;                   // V staging: wave w -> d rows w*16..+15
  u16* pw = &Ps[w * 16 * ALD];
  const int ntiles = qt + 1;
  for (int jt = 0; jt < ntiles; ++jt) {
    int j0 = jt * 64;
    const u16* ksrc = kb + (size_t)(j0 + krow_s) * 1024 + h * 64 + kcol_s;
    uint4 kv0 = *(const uint4*)ksrc;
    uint4 kv1 = *(const uint4*)(ksrc + 8);
    const u16* vsrc = vb + (size_t)(j0 + vkey) * 1024 + h * 64 + vd0;
    uint4 vv0 = *(const uint4*)vsrc;
    uint4 vv1 = *(const uint4*)(vsrc + 8);
    __syncthreads();   // protect prev-iter LDS reads
    *(uint4*)&Ks[krow_s * ALD + kcol_s] = kv0;
    *(uint4*)&Ks[krow_s * ALD + kcol_s + 8] = kv1;
    u16 vtmp[16];
    *(uint4*)&vtmp[0] = vv0;
    *(uint4*)&vtmp[8] = vv1;
#pragma unroll
    for (int i = 0; i < 16; ++i)
      Vt[(vd0 + i) * ALD + vkey] = vtmp[i];
    __syncthreads();
    // ---- scores: S[m][n] = sum_d Q[m][d] K[j0+n][d]
    f32x4 S[4] = {};
#pragma unroll
    for (int nt = 0; nt < 4; ++nt) {
      bf16x8 b0 = *(const bf16x8*)&Ks[(nt * 16 + m16) * ALD + q * 8];
      bf16x8 b1 = *(const bf16x8*)&Ks[(nt * 16 + m16) * ALD + 32 + q * 8];
      S[nt] = __builtin_amdgcn_mfma_f32_16x16x32_bf16(qa0, b0, S[nt], 0, 0, 0);
      S[nt] = __builtin_amdgcn_mfma_f32_16x16x32_bf16(qa1, b1, S[nt], 0, 0, 0);
    }
    // ---- exp + causal mask (only last tile crosses diagonal), row sums, P -> LDS
    bool diag = (jt == qt);
    float tmp[4] = {0.f, 0.f, 0.f, 0.f};
#pragma unroll
    for (int nt = 0; nt < 4; ++nt) {
      int j = j0 + nt * 16 + m16;
#pragma unroll
      for (int r = 0; r < 4; ++r) {
        float p = __expf(S[nt][r] * 0.12f);
        if (diag && (j > trow + r)) p = 0.f;
        tmp[r] += p;
        pw[(q * 4 + r) * ALD + nt * 16 + m16] = f2bf(p);
      }
    }
#pragma unroll
    for (int r = 0; r < 4; ++r) {
      float s = tmp[r];
      s += __shfl_xor(s, 1); s += __shfl_xor(s, 2);
      s += __shfl_xor(s, 4); s += __shfl_xor(s, 8);
      lsum[r] += s;
    }
    // ---- P C-layout -> A-layout via wave-private LDS (no barrier needed)
    bf16x8 pa0 = *(const bf16x8*)&pw[m16 * ALD + q * 8];
    bf16x8 pa1 = *(const bf16x8*)&pw[m16 * ALD + 32 + q * 8];
    // ---- PV: Y[m][d] += sum_k P[m][k] V[j0+k][d]
#pragma unroll
    for (int nt = 0; nt < 4; ++nt) {
      bf16x8 b0 = *(const bf16x8*)&Vt[(nt * 16 + m16) * ALD + q * 8];
      bf16x8 b1 = *(const bf16x8*)&Vt[(nt * 16 + m16) * ALD + 32 + q * 8];
      Yacc[nt] = __builtin_amdgcn_mfma_f32_16x16x32_bf16(pa0, b0, Yacc[nt], 0, 0, 0);
      Yacc[nt] = __builtin_amdgcn_mfma_f32_16x16x32_bf16(pa1, b1, Yacc[nt], 0, 0, 0);
    }
  }
  // ---- epilogue: y = Y / lsum, write bf16
#pragma unroll
  for (int r = 0; r < 4; ++r) {
    float inv = __builtin_amdgcn_rcpf(lsum[r]);
    int t = trow + r;
#pragma unroll
    for (int nt = 0; nt < 4; ++nt)
      yb[(size_t)t * 1024 + h * 64 + nt * 16 + m16] = f2bf(Yacc[nt][r] * inv);
  }
}

extern "C" void kernel_launch(void* const* d_in, const int* in_sizes, int n_in,
                              void* d_out, int out_size, void* d_ws, size_t ws_size,
                              hipStream_t stream) {
  const float* x   = (const float*)d_in[0];
  const float* Wq  = (const float*)d_in[1];
  const float* Wk  = (const float*)d_in[2];
  const float* Wv  = (const float*)d_in[3];
  const float* Wo  = (const float*)d_in[4];
  const float* sqk = (const float*)d_in[5];
  float* out = (float*)d_out;
  char* ws = (char*)d_ws;

  // workspace layout (40 MB), with lifetime-based reuse:
  //  0- 4 MB: xb (bf16 x)         -> qb16 after QKV gemm
  //  4-12 MB: Wt (4x bf16 [n][k])
  // 12-20 MB: q fp32              -> kb16 (12-16) + vb16 (16-20) after normrope_q
  // 20-28 MB: k fp32
  // 28-36 MB: v fp32
  // 36-40 MB: yb (bf16 attention out)
  u16*   xb   = (u16*)ws;
  u16*   Wt   = (u16*)(ws + ((size_t)4 << 20));
  float* qf   = (float*)(ws + ((size_t)12 << 20));
  float* kf   = (float*)(ws + ((size_t)20 << 20));
  float* vf   = (float*)(ws + ((size_t)28 << 20));
  u16*   yb   = (u16*)(ws + ((size_t)36 << 20));
  u16*   qb16 = (u16*)ws;                          // reuses xb
  u16*   kb16 = (u16*)(ws + ((size_t)12 << 20));   // reuses qf (dead)
  u16*   vb16 = (u16*)(ws + ((size_t)16 << 20));   // reuses qf (dead)

  cast_kernel<<<2048, 256, 0, stream>>>(x, xb, 2048 * 1024);
  transcast<<<dim3(16, 16, 4), 256, 0, stream>>>(Wq, Wk, Wv, Wo, Wt);
  gemm_bf16<<<dim3(1024 / BN, 2048 / BM, 3), 256, 0, stream>>>(
      xb, Wt, qf, 1024, 1024, (size_t)1024 * 1024, (size_t)2048 * 1024);
  normrope<<<2048 * 16 / 4, 256, 0, stream>>>(qf, qb16, sqk);   // qf -> qb16 (xb dead)
  normrope<<<2048 * 16 / 4, 256, 0, stream>>>(kf, kb16, sqk);   // kf -> kb16 (qf dead)
  cast_kernel<<<2048, 256, 0, stream>>>(vf, vb16, 2048 * 1024);
  attn_mfma<<<dim3(16, 32), 256, 0, stream>>>(qb16, kb16, vb16, yb);
  gemm_bf16<<<dim3(1024 / BN, 2048 / BM, 1), 256, 0, stream>>>(
      yb, Wt + (size_t)3 * 1024 * 1024, out, 1024, 1024, 0, 0);
}

// Round 3
// 200.520 us; speedup vs baseline: 3.9509x; 1.0041x over previous
//
#include <hip/hip_runtime.h>

typedef unsigned short u16;
typedef unsigned int u32;
typedef __attribute__((ext_vector_type(8))) short bf16x8;
typedef __attribute__((ext_vector_type(4))) float f32x4;

__device__ __forceinline__ u16 f2bf(float x) {
  unsigned u = __float_as_uint(x);
  u += 0x7fffu + ((u >> 16) & 1u);   // RNE
  return (u16)(u >> 16);
}
__device__ __forceinline__ float bf2f(u16 z) {
  return __uint_as_float((u32)z << 16);
}

// ---------------- cast fp32 -> bf16 (RNE); n divisible by 1024 ----------------
__global__ __launch_bounds__(256) void cast_kernel(const float* __restrict__ in,
                                                   u16* __restrict__ out, int n) {
  int i = (blockIdx.x * 256 + threadIdx.x) * 4;
  if (i >= n) return;
  float4 f = *(const float4*)(in + i);
  ushort4 o;
  o.x = f2bf(f.x); o.y = f2bf(f.y); o.z = f2bf(f.z); o.w = f2bf(f.w);
  *(ushort4*)(out + i) = o;
}

// ------------- transpose+cast 4 weights: W[k][n] fp32 -> Wt[n][k] bf16 -------------
__global__ __launch_bounds__(256) void transcast(const float* __restrict__ W0,
                                                 const float* __restrict__ W1,
                                                 const float* __restrict__ W2,
                                                 const float* __restrict__ W3,
                                                 u16* __restrict__ out) {
  __shared__ alignas(16) u16 ls[64 * 72];
  int z = blockIdx.z;
  const float* W = (z == 0) ? W0 : (z == 1) ? W1 : (z == 2) ? W2 : W3;
  u16* o = out + (size_t)z * (1024u * 1024u);
  int kt = blockIdx.y * 64, nt = blockIdx.x * 64;
  int tid = threadIdx.x;
  int r = tid >> 2, c0 = (tid & 3) * 16;
  const float* src = W + (size_t)(kt + r) * 1024 + nt + c0;
  u16 tmp[16];
#pragma unroll
  for (int c = 0; c < 16; c += 4) {
    float4 f = *(const float4*)(src + c);
    tmp[c + 0] = f2bf(f.x); tmp[c + 1] = f2bf(f.y);
    tmp[c + 2] = f2bf(f.z); tmp[c + 3] = f2bf(f.w);
  }
#pragma unroll
  for (int c = 0; c < 16; ++c) ls[r * 72 + c0 + c] = tmp[c];
  __syncthreads();
#pragma unroll
  for (int pass = 0; pass < 4; ++pass) {
    int n = pass * 16 + (tid >> 4);
    int kk = (tid & 15) * 4;
    ushort4 val;
    val.x = ls[(kk + 0) * 72 + n];
    val.y = ls[(kk + 1) * 72 + n];
    val.z = ls[(kk + 2) * 72 + n];
    val.w = ls[(kk + 3) * 72 + n];
    *(ushort4*)(o + (size_t)(nt + n) * 1024 + kt + kk) = val;
  }
}

// ---- transpose+cast V: vf fp32 [t][h*64+d] -> vt bf16 [h*64+d][t] ----
__global__ __launch_bounds__(256) void vtrans(const float* __restrict__ vf,
                                              u16* __restrict__ vt) {
  __shared__ alignas(16) u16 ls[64 * 72];
  int t0 = blockIdx.x * 64, h = blockIdx.y;
  int tid = threadIdx.x;
  int r = tid >> 2, c0 = (tid & 3) * 16;
  const float* src = vf + (size_t)(t0 + r) * 1024 + h * 64 + c0;
  u16 tmp[16];
#pragma unroll
  for (int c = 0; c < 16; c += 4) {
    float4 f = *(const float4*)(src + c);
    tmp[c + 0] = f2bf(f.x); tmp[c + 1] = f2bf(f.y);
    tmp[c + 2] = f2bf(f.z); tmp[c + 3] = f2bf(f.w);
  }
#pragma unroll
  for (int c = 0; c < 16; ++c) ls[r * 72 + c0 + c] = tmp[c];
  __syncthreads();
#pragma unroll
  for (int pass = 0; pass < 4; ++pass) {
    int n = pass * 16 + (tid >> 4);   // d within head
    int kk = (tid & 15) * 4;          // t within tile
    ushort4 val;
    val.x = ls[(kk + 0) * 72 + n];
    val.y = ls[(kk + 1) * 72 + n];
    val.z = ls[(kk + 2) * 72 + n];
    val.w = ls[(kk + 3) * 72 + n];
    *(ushort4*)(vt + (size_t)(h * 64 + n) * 2048 + t0 + kk) = val;
  }
}

// ------------- bf16 MFMA GEMM 128x128: C[M][N] = A[M][K] * B[N][K]^T -------------
#define GLD 40  // LDS stride: rows alias at +8 -> 2-way on banks (free)
__global__ __launch_bounds__(256) void gemm128(const u16* __restrict__ A,
                                               const u16* __restrict__ Bmat,
                                               float* __restrict__ C,
                                               int K, int N, size_t bz, size_t cz) {
  __shared__ alignas(16) u16 As[128 * GLD];
  __shared__ alignas(16) u16 Bs[128 * GLD];
  const u16* B = Bmat + (size_t)blockIdx.z * bz;
  float* Cz = C + (size_t)blockIdx.z * cz;
  int tid = threadIdx.x;
  int bm = blockIdx.y * 128, bn = blockIdx.x * 128;
  int lane = tid & 63, w = tid >> 6;
  int wm = (w >> 1) * 64, wn = (w & 1) * 64;
  int m16 = lane & 15, q = lane >> 4;
  f32x4 acc[4][4] = {};
  int srow = tid >> 1, scol = (tid & 1) * 16;
  const u16* aptr = A + (size_t)(bm + srow) * K + scol;
  const u16* bptr = B + (size_t)(bn + srow) * K + scol;
  for (int k0 = 0; k0 < K; k0 += 32) {
    uint4 a0 = *(const uint4*)(aptr + k0);
    uint4 a1 = *(const uint4*)(aptr + k0 + 8);
    uint4 b0 = *(const uint4*)(bptr + k0);
    uint4 b1 = *(const uint4*)(bptr + k0 + 8);
    __syncthreads();
    *(uint4*)&As[srow * GLD + scol] = a0;
    *(uint4*)&As[srow * GLD + scol + 8] = a1;
    *(uint4*)&Bs[srow * GLD + scol] = b0;
    *(uint4*)&Bs[srow * GLD + scol + 8] = b1;
    __syncthreads();
    bf16x8 af[4], bfr[4];
#pragma unroll
    for (int mt = 0; mt < 4; ++mt)
      af[mt] = *(const bf16x8*)&As[(wm + mt * 16 + m16) * GLD + q * 8];
#pragma unroll
    for (int nt = 0; nt < 4; ++nt)
      bfr[nt] = *(const bf16x8*)&Bs[(wn + nt * 16 + m16) * GLD + q * 8];
#pragma unroll
    for (int mt = 0; mt < 4; ++mt)
#pragma unroll
      for (int nt = 0; nt < 4; ++nt)
        acc[mt][nt] = __builtin_amdgcn_mfma_f32_16x16x32_bf16(af[mt], bfr[nt], acc[mt][nt], 0, 0, 0);
  }
#pragma unroll
  for (int mt = 0; mt < 4; ++mt)
#pragma unroll
    for (int nt = 0; nt < 4; ++nt)
#pragma unroll
      for (int r = 0; r < 4; ++r) {
        int row = bm + wm + mt * 16 + q * 4 + r;
        int col = bn + wn + nt * 16 + m16;
        Cz[(size_t)row * N + col] = acc[mt][nt][r];
      }
}

// ------- cosine-norm * s_eff + rotary: read fp32 src, write bf16 dst -------
__global__ __launch_bounds__(256) void normrope(const float* __restrict__ src,
                                                u16* __restrict__ dst,
                                                const float* __restrict__ s_qk) {
  int tid = threadIdx.x;
  int lane = tid & 63;
  int idx = blockIdx.x * 4 + (tid >> 6);   // t*16 + h
  int t = idx >> 4, h = idx & 15;
  const float* p = src + (size_t)t * 1024 + h * 64;
  float x = p[lane];
  float ss = x * x;
#pragma unroll
  for (int m = 32; m; m >>= 1) ss += __shfl_xor(ss, m);
  float xn = x * rsqrtf(ss + 1e-12f) * (s_qk[h * 64 + lane] * 32.0f);  // sqrt(1024)=32
  float other = __shfl_xor(xn, 32);
  int i = lane & 31;
  float fr = (i < 16) ? exp2f(-10.0f * (float)i / 15.0f) : 0.0f;  // (1/1024)^(i/15)
  float th = (float)t * fr;
  float c = cosf(th), s = sinf(th);
  float sgn = (lane < 32) ? s : -s;  // y1 = x1*c + x2*s ; y2 = x2*c - x1*s
  dst[(size_t)t * 1024 + h * 64 + lane] = f2bf(xn * c + other * sgn);
}

// ------------- MFMA flash attention, split-key partials ----------
// grid (h=16, 32 qt, 4 chunks); block 256 (4 waves), 64 q-rows per block.
// no-rescale softmax (|score*0.12| <= 0.27): partials combine exactly as
// y = sum_c Z_c * L_c / sum_c L_c  with Z_c the per-chunk-normalized output.
#define ALD 72
__global__ __launch_bounds__(256) void attn_mfma(const u16* __restrict__ qb,
                                                 const u16* __restrict__ kb,
                                                 const u16* __restrict__ vt,
                                                 u16* __restrict__ Zp,
                                                 float* __restrict__ Lp) {
  __shared__ alignas(16) u16 Ks[64 * ALD];        // K tile [key][d]
  __shared__ alignas(16) u16 Vt[64 * ALD];        // V tile [d][key] (pre-transposed src)
  __shared__ alignas(16) u16 Ps[4 * 16 * ALD];    // per-wave P [row][key]
  int h = blockIdx.x;
  int qt = 31 - blockIdx.y;            // heavy q-tiles dispatch first
  int c = blockIdx.z;
  int w4 = (qt + 4) >> 2;              // chunk width = ceil((qt+1)/4) key-tiles
  int jb = c * w4;
  int je = min(jb + w4, qt + 1);
  int slot = (h * 32 + qt) * 4 + c;
  int t0 = qt * 64;
  int tid = threadIdx.x;
  int lane = tid & 63, w = tid >> 6;
  int m16 = lane & 15, q = lane >> 4;
  u16* zout = Zp + (size_t)slot * 4096;
  float* lout = Lp + (size_t)slot * 64;
  if (jb >= je) {                      // empty chunk: zero its slot
#pragma unroll
    for (int nt = 0; nt < 4; ++nt)
#pragma unroll
      for (int r = 0; r < 4; ++r)
        zout[(w * 16 + q * 4 + r) * 64 + nt * 16 + m16] = 0;
    if (m16 == 0)
#pragma unroll
      for (int r = 0; r < 4; ++r) lout[w * 16 + q * 4 + r] = 0.f;
    return;
  }
  const u16* qrow = qb + (size_t)(t0 + w * 16 + m16) * 1024 + h * 64;
  bf16x8 qa0 = *(const bf16x8*)(qrow + q * 8);
  bf16x8 qa1 = *(const bf16x8*)(qrow + 32 + q * 8);
  f32x4 Yacc[4] = {};
  float lsum[4] = {0.f, 0.f, 0.f, 0.f};
  int trow = t0 + w * 16 + q * 4;
  int krow_s = tid >> 2, kcol_s = (tid & 3) * 16;   // K staging: 4 thr/row
  int vd_s = tid >> 2, vk_s = (tid & 3) * 16;       // V staging: [d][key] rows
  u16* pw = &Ps[w * 16 * ALD];
  for (int jt = jb; jt < je; ++jt) {
    int j0 = jt * 64;
    const u16* ksrc = kb + (size_t)(j0 + krow_s) * 1024 + h * 64 + kcol_s;
    uint4 kv0 = *(const uint4*)ksrc;
    uint4 kv1 = *(const uint4*)(ksrc + 8);
    const u16* vsrc = vt + (size_t)(h * 64 + vd_s) * 2048 + j0 + vk_s;
    uint4 vv0 = *(const uint4*)vsrc;
    uint4 vv1 = *(const uint4*)(vsrc + 8);
    __syncthreads();   // protect prev-iter LDS reads
    *(uint4*)&Ks[krow_s * ALD + kcol_s] = kv0;
    *(uint4*)&Ks[krow_s * ALD + kcol_s + 8] = kv1;
    *(uint4*)&Vt[vd_s * ALD + vk_s] = vv0;
    *(uint4*)&Vt[vd_s * ALD + vk_s + 8] = vv1;
    __syncthreads();
    // ---- scores: S[m][n] = sum_d Q[m][d] K[j0+n][d]
    f32x4 S[4] = {};
#pragma unroll
    for (int nt = 0; nt < 4; ++nt) {
      bf16x8 b0 = *(const bf16x8*)&Ks[(nt * 16 + m16) * ALD + q * 8];
      bf16x8 b1 = *(const bf16x8*)&Ks[(nt * 16 + m16) * ALD + 32 + q * 8];
      S[nt] = __builtin_amdgcn_mfma_f32_16x16x32_bf16(qa0, b0, S[nt], 0, 0, 0);
      S[nt] = __builtin_amdgcn_mfma_f32_16x16x32_bf16(qa1, b1, S[nt], 0, 0, 0);
    }
    // ---- exp + causal mask, row sums, P -> LDS
    bool diag = (jt == qt);
    float tmp[4] = {0.f, 0.f, 0.f, 0.f};
#pragma unroll
    for (int nt = 0; nt < 4; ++nt) {
      int j = j0 + nt * 16 + m16;
#pragma unroll
      for (int r = 0; r < 4; ++r) {
        float p = __expf(S[nt][r] * 0.12f);
        if (diag && (j > trow + r)) p = 0.f;
        tmp[r] += p;
        pw[(q * 4 + r) * ALD + nt * 16 + m16] = f2bf(p);
      }
    }
#pragma unroll
    for (int r = 0; r < 4; ++r) {
      float s = tmp[r];
      s += __shfl_xor(s, 1); s += __shfl_xor(s, 2);
      s += __shfl_xor(s, 4); s += __shfl_xor(s, 8);
      lsum[r] += s;
    }
    // ---- P C-layout -> A-layout via wave-private LDS (no barrier needed)
    bf16x8 pa0 = *(const bf16x8*)&pw[m16 * ALD + q * 8];
    bf16x8 pa1 = *(const bf16x8*)&pw[m16 * ALD + 32 + q * 8];
    // ---- PV: Y[m][d] += sum_k P[m][k] V[k][d]
#pragma unroll
    for (int nt = 0; nt < 4; ++nt) {
      bf16x8 b0 = *(const bf16x8*)&Vt[(nt * 16 + m16) * ALD + q * 8];
      bf16x8 b1 = *(const bf16x8*)&Vt[(nt * 16 + m16) * ALD + 32 + q * 8];
      Yacc[nt] = __builtin_amdgcn_mfma_f32_16x16x32_bf16(pa0, b0, Yacc[nt], 0, 0, 0);
      Yacc[nt] = __builtin_amdgcn_mfma_f32_16x16x32_bf16(pa1, b1, Yacc[nt], 0, 0, 0);
    }
  }
  // ---- epilogue: Z = Y / L (per-chunk normalized), store Z bf16 + L fp32
#pragma unroll
  for (int r = 0; r < 4; ++r) {
    float inv = __builtin_amdgcn_rcpf(lsum[r]);
#pragma unroll
    for (int nt = 0; nt < 4; ++nt)
      zout[(w * 16 + q * 4 + r) * 64 + nt * 16 + m16] = f2bf(Yacc[nt][r] * inv);
  }
  if (m16 == 0)
#pragma unroll
    for (int r = 0; r < 4; ++r) lout[w * 16 + q * 4 + r] = lsum[r];
}

// ------- combine partials: yb[t][h*64+d] = sum_c Z*L / sum_c L -------
__global__ __launch_bounds__(256) void combine(const u16* __restrict__ Zp,
                                               const float* __restrict__ Lp,
                                               u16* __restrict__ yb) {
  int tid = threadIdx.x;
  int g = blockIdx.x * 4 + (tid >> 6);   // row id: h*2048 + t
  int d = tid & 63;
  int h = g >> 11, t = g & 2047;
  int qt = t >> 6, r = t & 63;
  int base = (h * 32 + qt) * 4;
  float acc = 0.f, lt = 0.f;
#pragma unroll
  for (int c = 0; c < 4; ++c) {
    float L = Lp[(size_t)(base + c) * 64 + r];
    float z = bf2f(Zp[(size_t)(base + c) * 4096 + r * 64 + d]);
    acc += z * L;
    lt += L;
  }
  yb[(size_t)t * 1024 + h * 64 + d] = f2bf(acc / lt);
}

extern "C" void kernel_launch(void* const* d_in, const int* in_sizes, int n_in,
                              void* d_out, int out_size, void* d_ws, size_t ws_size,
                              hipStream_t stream) {
  const float* x   = (const float*)d_in[0];
  const float* Wq  = (const float*)d_in[1];
  const float* Wk  = (const float*)d_in[2];
  const float* Wv  = (const float*)d_in[3];
  const float* Wo  = (const float*)d_in[4];
  const float* sqk = (const float*)d_in[5];
  float* out = (float*)d_out;
  char* ws = (char*)d_ws;

  // workspace layout (37 MB peak), lifetime-based reuse:
  //  0- 4: xb (bf16 x)        -> qb16 after QKV gemm
  //  4-12: Wt (4x bf16 [n][k]; o-proj weight at 10-12) ; 4-8 -> yb after attn
  // 12-20: qf fp32            -> kb16 (12-16) + vt16 (16-20)
  // 20-28: kf fp32            -> Zp (20-36) after normrope_k/vtrans
  // 28-36: vf fp32
  // 36-36.5: Lp
  u16*   xb   = (u16*)ws;
  u16*   Wt   = (u16*)(ws + ((size_t)4 << 20));
  float* qf   = (float*)(ws + ((size_t)12 << 20));
  float* kf   = (float*)(ws + ((size_t)20 << 20));
  float* vf   = (float*)(ws + ((size_t)28 << 20));
  u16*   qb16 = (u16*)ws;
  u16*   kb16 = (u16*)(ws + ((size_t)12 << 20));
  u16*   vt16 = (u16*)(ws + ((size_t)16 << 20));
  u16*   Zp   = (u16*)(ws + ((size_t)20 << 20));
  float* Lp   = (float*)(ws + ((size_t)36 << 20));
  u16*   yb   = (u16*)(ws + ((size_t)4 << 20));
  u16*   Wto  = Wt + (size_t)3 * 1024 * 1024;

  cast_kernel<<<2048, 256, 0, stream>>>(x, xb, 2048 * 1024);
  transcast<<<dim3(16, 16, 4), 256, 0, stream>>>(Wq, Wk, Wv, Wo, Wt);
  gemm128<<<dim3(8, 16, 3), 256, 0, stream>>>(
      xb, Wt, qf, 1024, 1024, (size_t)1024 * 1024, (size_t)2048 * 1024);
  normrope<<<8192, 256, 0, stream>>>(qf, qb16, sqk);   // qf -> qb16 (xb dead)
  normrope<<<8192, 256, 0, stream>>>(kf, kb16, sqk);   // kf -> kb16 (qf dead)
  vtrans<<<dim3(32, 16), 256, 0, stream>>>(vf, vt16);  // vf -> vt16 (qf dead)
  attn_mfma<<<dim3(16, 32, 4), 256, 0, stream>>>(qb16, kb16, vt16, Zp, Lp);
  combine<<<8192, 256, 0, stream>>>(Zp, Lp, yb);       // -> yb (Wt q/k dead)
  gemm128<<<dim3(8, 16, 1), 256, 0, stream>>>(yb, Wto, out, 1024, 1024, 0, 0);
}

// Round 4
// 180.185 us; speedup vs baseline: 4.3968x; 1.1129x over previous
//
#include <hip/hip_runtime.h>

typedef unsigned short u16;
typedef unsigned int u32;
typedef __attribute__((ext_vector_type(8))) short bf16x8;
typedef __attribute__((ext_vector_type(4))) float f32x4;

__device__ __forceinline__ u16 f2bf(float x) {
  unsigned u = __float_as_uint(x);
  u += 0x7fffu + ((u >> 16) & 1u);   // RNE
  return (u16)(u >> 16);
}
__device__ __forceinline__ float bf2f(u16 z) {
  return __uint_as_float((u32)z << 16);
}

// ---------------- cast fp32 -> bf16 (RNE); n divisible by 1024 ----------------
__global__ __launch_bounds__(256) void cast_kernel(const float* __restrict__ in,
                                                   u16* __restrict__ out, int n) {
  int i = (blockIdx.x * 256 + threadIdx.x) * 4;
  if (i >= n) return;
  float4 f = *(const float4*)(in + i);
  ushort4 o;
  o.x = f2bf(f.x); o.y = f2bf(f.y); o.z = f2bf(f.z); o.w = f2bf(f.w);
  *(ushort4*)(out + i) = o;
}

// ------------- transpose+cast 4 weights: W[k][n] fp32 -> Wt[n][k] bf16 -------------
__global__ __launch_bounds__(256) void transcast(const float* __restrict__ W0,
                                                 const float* __restrict__ W1,
                                                 const float* __restrict__ W2,
                                                 const float* __restrict__ W3,
                                                 u16* __restrict__ out) {
  __shared__ alignas(16) u16 ls[64 * 72];
  int z = blockIdx.z;
  const float* W = (z == 0) ? W0 : (z == 1) ? W1 : (z == 2) ? W2 : W3;
  u16* o = out + (size_t)z * (1024u * 1024u);
  int kt = blockIdx.y * 64, nt = blockIdx.x * 64;
  int tid = threadIdx.x;
  int r = tid >> 2, c0 = (tid & 3) * 16;
  const float* src = W + (size_t)(kt + r) * 1024 + nt + c0;
  u16 tmp[16];
#pragma unroll
  for (int c = 0; c < 16; c += 4) {
    float4 f = *(const float4*)(src + c);
    tmp[c + 0] = f2bf(f.x); tmp[c + 1] = f2bf(f.y);
    tmp[c + 2] = f2bf(f.z); tmp[c + 3] = f2bf(f.w);
  }
#pragma unroll
  for (int c = 0; c < 16; ++c) ls[r * 72 + c0 + c] = tmp[c];
  __syncthreads();
#pragma unroll
  for (int pass = 0; pass < 4; ++pass) {
    int n = pass * 16 + (tid >> 4);
    int kk = (tid & 15) * 4;
    ushort4 val;
    val.x = ls[(kk + 0) * 72 + n];
    val.y = ls[(kk + 1) * 72 + n];
    val.z = ls[(kk + 2) * 72 + n];
    val.w = ls[(kk + 3) * 72 + n];
    *(ushort4*)(o + (size_t)(nt + n) * 1024 + kt + kk) = val;
  }
}

// ---- transpose+cast V (sum of 2 split-K partials): -> vt bf16 [h*64+d][t] ----
__global__ __launch_bounds__(256) void vtrans(const float* __restrict__ v0,
                                              const float* __restrict__ v1,
                                              u16* __restrict__ vt) {
  __shared__ alignas(16) u16 ls[64 * 72];
  int t0 = blockIdx.x * 64, h = blockIdx.y;
  int tid = threadIdx.x;
  int r = tid >> 2, c0 = (tid & 3) * 16;
  size_t off = (size_t)(t0 + r) * 1024 + h * 64 + c0;
  u16 tmp[16];
#pragma unroll
  for (int c = 0; c < 16; c += 4) {
    float4 fa = *(const float4*)(v0 + off + c);
    float4 fb = *(const float4*)(v1 + off + c);
    tmp[c + 0] = f2bf(fa.x + fb.x); tmp[c + 1] = f2bf(fa.y + fb.y);
    tmp[c + 2] = f2bf(fa.z + fb.z); tmp[c + 3] = f2bf(fa.w + fb.w);
  }
#pragma unroll
  for (int c = 0; c < 16; ++c) ls[r * 72 + c0 + c] = tmp[c];
  __syncthreads();
#pragma unroll
  for (int pass = 0; pass < 4; ++pass) {
    int n = pass * 16 + (tid >> 4);   // d within head
    int kk = (tid & 15) * 4;          // t within tile
    ushort4 val;
    val.x = ls[(kk + 0) * 72 + n];
    val.y = ls[(kk + 1) * 72 + n];
    val.z = ls[(kk + 2) * 72 + n];
    val.w = ls[(kk + 3) * 72 + n];
    *(ushort4*)(vt + (size_t)(h * 64 + n) * 2048 + t0 + kk) = val;
  }
}

// ------- bf16 MFMA GEMM 128x128, split-K=2: Cz = A[:, kh*KH:+KH] * B^T -------
// grid.z = 2*nproj; proj = z>>1 selects B matrix (stride bz); kh = z&1.
// Each z writes its own fp32 partial buffer at C + z*cz.
#define GLD 40  // LDS stride: rows alias at +8 -> 2-way on banks (free)
#define KH 512
__global__ __launch_bounds__(256) void gemm128(const u16* __restrict__ A,
                                               const u16* __restrict__ Bmat,
                                               float* __restrict__ C,
                                               int K, int N, size_t bz, size_t cz) {
  __shared__ alignas(16) u16 As[128 * GLD];
  __shared__ alignas(16) u16 Bs[128 * GLD];
  int z = blockIdx.z;
  const u16* B = Bmat + (size_t)(z >> 1) * bz;
  float* Cz = C + (size_t)z * cz;
  int kbeg = (z & 1) * KH;
  int tid = threadIdx.x;
  int bm = blockIdx.y * 128, bn = blockIdx.x * 128;
  int lane = tid & 63, w = tid >> 6;
  int wm = (w >> 1) * 64, wn = (w & 1) * 64;
  int m16 = lane & 15, q = lane >> 4;
  f32x4 acc[4][4] = {};
  int srow = tid >> 1, scol = (tid & 1) * 16;
  const u16* aptr = A + (size_t)(bm + srow) * K + scol;
  const u16* bptr = B + (size_t)(bn + srow) * K + scol;
  for (int k0 = kbeg; k0 < kbeg + KH; k0 += 32) {
    uint4 a0 = *(const uint4*)(aptr + k0);
    uint4 a1 = *(const uint4*)(aptr + k0 + 8);
    uint4 b0 = *(const uint4*)(bptr + k0);
    uint4 b1 = *(const uint4*)(bptr + k0 + 8);
    __syncthreads();
    *(uint4*)&As[srow * GLD + scol] = a0;
    *(uint4*)&As[srow * GLD + scol + 8] = a1;
    *(uint4*)&Bs[srow * GLD + scol] = b0;
    *(uint4*)&Bs[srow * GLD + scol + 8] = b1;
    __syncthreads();
    bf16x8 af[4], bfr[4];
#pragma unroll
    for (int mt = 0; mt < 4; ++mt)
      af[mt] = *(const bf16x8*)&As[(wm + mt * 16 + m16) * GLD + q * 8];
#pragma unroll
    for (int nt = 0; nt < 4; ++nt)
      bfr[nt] = *(const bf16x8*)&Bs[(wn + nt * 16 + m16) * GLD + q * 8];
#pragma unroll
    for (int mt = 0; mt < 4; ++mt)
#pragma unroll
      for (int nt = 0; nt < 4; ++nt)
        acc[mt][nt] = __builtin_amdgcn_mfma_f32_16x16x32_bf16(af[mt], bfr[nt], acc[mt][nt], 0, 0, 0);
  }
#pragma unroll
  for (int mt = 0; mt < 4; ++mt)
#pragma unroll
    for (int nt = 0; nt < 4; ++nt)
#pragma unroll
      for (int r = 0; r < 4; ++r) {
        int row = bm + wm + mt * 16 + q * 4 + r;
        int col = bn + wn + nt * 16 + m16;
        Cz[(size_t)row * N + col] = acc[mt][nt][r];
      }
}

// ---- out = p0 + p1 (o-proj split-K reduce), fp32, n div by 1024 ----
__global__ __launch_bounds__(256) void addout(const float* __restrict__ p0,
                                              const float* __restrict__ p1,
                                              float* __restrict__ out, int n) {
  int i = (blockIdx.x * 256 + threadIdx.x) * 4;
  if (i >= n) return;
  float4 a = *(const float4*)(p0 + i);
  float4 b = *(const float4*)(p1 + i);
  float4 o = {a.x + b.x, a.y + b.y, a.z + b.z, a.w + b.w};
  *(float4*)(out + i) = o;
}

// -- cosine-norm * s_eff + rotary on (partial0+partial1): write bf16 dst --
// blockIdx.y: 0 -> q, 1 -> k
__global__ __launch_bounds__(256) void normrope(const float* __restrict__ q0,
                                                const float* __restrict__ q1,
                                                const float* __restrict__ k0,
                                                const float* __restrict__ k1,
                                                u16* __restrict__ qd,
                                                u16* __restrict__ kd,
                                                const float* __restrict__ s_qk) {
  int tid = threadIdx.x;
  int lane = tid & 63;
  int idx = blockIdx.x * 4 + (tid >> 6);   // t*16 + h
  int t = idx >> 4, h = idx & 15;
  const float* a = blockIdx.y ? k0 : q0;
  const float* b = blockIdx.y ? k1 : q1;
  u16* dst = blockIdx.y ? kd : qd;
  size_t off = (size_t)t * 1024 + h * 64 + lane;
  float x = a[off] + b[off];
  float ss = x * x;
#pragma unroll
  for (int m = 32; m; m >>= 1) ss += __shfl_xor(ss, m);
  float xn = x * rsqrtf(ss + 1e-12f) * (s_qk[h * 64 + lane] * 32.0f);  // sqrt(1024)=32
  float other = __shfl_xor(xn, 32);
  int i = lane & 31;
  float fr = (i < 16) ? exp2f(-10.0f * (float)i / 15.0f) : 0.0f;  // (1/1024)^(i/15)
  float th = (float)t * fr;
  float c = cosf(th), s = sinf(th);
  float sgn = (lane < 32) ? s : -s;  // y1 = x1*c + x2*s ; y2 = x2*c - x1*s
  dst[off] = f2bf(xn * c + other * sgn);
}

// ------------- MFMA flash attention, split-key partials ----------
// grid (h=16, 32 qt, 4 chunks); block 256 (4 waves), 64 q-rows per block.
// no-rescale softmax (|score*0.12| <= 0.27): partials combine exactly as
// y = sum_c Z_c * L_c / sum_c L_c  with Z_c the per-chunk-normalized output.
#define ALD 72
__global__ __launch_bounds__(256) void attn_mfma(const u16* __restrict__ qb,
                                                 const u16* __restrict__ kb,
                                                 const u16* __restrict__ vt,
                                                 u16* __restrict__ Zp,
                                                 float* __restrict__ Lp) {
  __shared__ alignas(16) u16 Ks[64 * ALD];        // K tile [key][d]
  __shared__ alignas(16) u16 Vt[64 * ALD];        // V tile [d][key] (pre-transposed src)
  __shared__ alignas(16) u16 Ps[4 * 16 * ALD];    // per-wave P [row][key]
  int h = blockIdx.x;
  int qt = 31 - blockIdx.y;            // heavy q-tiles dispatch first
  int c = blockIdx.z;
  int w4 = (qt + 4) >> 2;              // chunk width = ceil((qt+1)/4) key-tiles
  int jb = c * w4;
  int je = min(jb + w4, qt + 1);
  int slot = (h * 32 + qt) * 4 + c;
  int t0 = qt * 64;
  int tid = threadIdx.x;
  int lane = tid & 63, w = tid >> 6;
  int m16 = lane & 15, q = lane >> 4;
  u16* zout = Zp + (size_t)slot * 4096;
  float* lout = Lp + (size_t)slot * 64;
  if (jb >= je) {                      // empty chunk: zero its slot
#pragma unroll
    for (int nt = 0; nt < 4; ++nt)
#pragma unroll
      for (int r = 0; r < 4; ++r)
        zout[(w * 16 + q * 4 + r) * 64 + nt * 16 + m16] = 0;
    if (m16 == 0)
#pragma unroll
      for (int r = 0; r < 4; ++r) lout[w * 16 + q * 4 + r] = 0.f;
    return;
  }
  const u16* qrow = qb + (size_t)(t0 + w * 16 + m16) * 1024 + h * 64;
  bf16x8 qa0 = *(const bf16x8*)(qrow + q * 8);
  bf16x8 qa1 = *(const bf16x8*)(qrow + 32 + q * 8);
  f32x4 Yacc[4] = {};
  float lsum[4] = {0.f, 0.f, 0.f, 0.f};
  int trow = t0 + w * 16 + q * 4;
  int krow_s = tid >> 2, kcol_s = (tid & 3) * 16;   // K staging: 4 thr/row
  int vd_s = tid >> 2, vk_s = (tid & 3) * 16;       // V staging: [d][key] rows
  u16* pw = &Ps[w * 16 * ALD];
  for (int jt = jb; jt < je; ++jt) {
    int j0 = jt * 64;
    const u16* ksrc = kb + (size_t)(j0 + krow_s) * 1024 + h * 64 + kcol_s;
    uint4 kv0 = *(const uint4*)ksrc;
    uint4 kv1 = *(const uint4*)(ksrc + 8);
    const u16* vsrc = vt + (size_t)(h * 64 + vd_s) * 2048 + j0 + vk_s;
    uint4 vv0 = *(const uint4*)vsrc;
    uint4 vv1 = *(const uint4*)(vsrc + 8);
    __syncthreads();   // protect prev-iter LDS reads
    *(uint4*)&Ks[krow_s * ALD + kcol_s] = kv0;
    *(uint4*)&Ks[krow_s * ALD + kcol_s + 8] = kv1;
    *(uint4*)&Vt[vd_s * ALD + vk_s] = vv0;
    *(uint4*)&Vt[vd_s * ALD + vk_s + 8] = vv1;
    __syncthreads();
    // ---- scores: S[m][n] = sum_d Q[m][d] K[j0+n][d]
    f32x4 S[4] = {};
#pragma unroll
    for (int nt = 0; nt < 4; ++nt) {
      bf16x8 b0 = *(const bf16x8*)&Ks[(nt * 16 + m16) * ALD + q * 8];
      bf16x8 b1 = *(const bf16x8*)&Ks[(nt * 16 + m16) * ALD + 32 + q * 8];
      S[nt] = __builtin_amdgcn_mfma_f32_16x16x32_bf16(qa0, b0, S[nt], 0, 0, 0);
      S[nt] = __builtin_amdgcn_mfma_f32_16x16x32_bf16(qa1, b1, S[nt], 0, 0, 0);
    }
    // ---- exp + causal mask, row sums, P -> LDS
    bool diag = (jt == qt);
    float tmp[4] = {0.f, 0.f, 0.f, 0.f};
#pragma unroll
    for (int nt = 0; nt < 4; ++nt) {
      int j = j0 + nt * 16 + m16;
#pragma unroll
      for (int r = 0; r < 4; ++r) {
        float p = __expf(S[nt][r] * 0.12f);
        if (diag && (j > trow + r)) p = 0.f;
        tmp[r] += p;
        pw[(q * 4 + r) * ALD + nt * 16 + m16] = f2bf(p);
      }
    }
#pragma unroll
    for (int r = 0; r < 4; ++r) {
      float s = tmp[r];
      s += __shfl_xor(s, 1); s += __shfl_xor(s, 2);
      s += __shfl_xor(s, 4); s += __shfl_xor(s, 8);
      lsum[r] += s;
    }
    // ---- P C-layout -> A-layout via wave-private LDS (no barrier needed)
    bf16x8 pa0 = *(const bf16x8*)&pw[m16 * ALD + q * 8];
    bf16x8 pa1 = *(const bf16x8*)&pw[m16 * ALD + 32 + q * 8];
    // ---- PV: Y[m][d] += sum_k P[m][k] V[k][d]
#pragma unroll
    for (int nt = 0; nt < 4; ++nt) {
      bf16x8 b0 = *(const bf16x8*)&Vt[(nt * 16 + m16) * ALD + q * 8];
      bf16x8 b1 = *(const bf16x8*)&Vt[(nt * 16 + m16) * ALD + 32 + q * 8];
      Yacc[nt] = __builtin_amdgcn_mfma_f32_16x16x32_bf16(pa0, b0, Yacc[nt], 0, 0, 0);
      Yacc[nt] = __builtin_amdgcn_mfma_f32_16x16x32_bf16(pa1, b1, Yacc[nt], 0, 0, 0);
    }
  }
  // ---- epilogue: Z = Y / L (per-chunk normalized), store Z bf16 + L fp32
#pragma unroll
  for (int r = 0; r < 4; ++r) {
    float inv = __builtin_amdgcn_rcpf(lsum[r]);
#pragma unroll
    for (int nt = 0; nt < 4; ++nt)
      zout[(w * 16 + q * 4 + r) * 64 + nt * 16 + m16] = f2bf(Yacc[nt][r] * inv);
  }
  if (m16 == 0)
#pragma unroll
    for (int r = 0; r < 4; ++r) lout[w * 16 + q * 4 + r] = lsum[r];
}

// ------- combine partials: yb[t][h*64+d] = sum_c Z*L / sum_c L -------
__global__ __launch_bounds__(256) void combine(const u16* __restrict__ Zp,
                                               const float* __restrict__ Lp,
                                               u16* __restrict__ yb) {
  int tid = threadIdx.x;
  int g = blockIdx.x * 4 + (tid >> 6);   // row id: h*2048 + t
  int d = tid & 63;
  int h = g >> 11, t = g & 2047;
  int qt = t >> 6, r = t & 63;
  int base = (h * 32 + qt) * 4;
  float acc = 0.f, lt = 0.f;
#pragma unroll
  for (int c = 0; c < 4; ++c) {
    float L = Lp[(size_t)(base + c) * 64 + r];
    float z = bf2f(Zp[(size_t)(base + c) * 4096 + r * 64 + d]);
    acc += z * L;
    lt += L;
  }
  yb[(size_t)t * 1024 + h * 64 + d] = f2bf(acc / lt);
}

extern "C" void kernel_launch(void* const* d_in, const int* in_sizes, int n_in,
                              void* d_out, int out_size, void* d_ws, size_t ws_size,
                              hipStream_t stream) {
  const float* x   = (const float*)d_in[0];
  const float* Wq  = (const float*)d_in[1];
  const float* Wk  = (const float*)d_in[2];
  const float* Wv  = (const float*)d_in[3];
  const float* Wo  = (const float*)d_in[4];
  const float* sqk = (const float*)d_in[5];
  float* out = (float*)d_out;
  char* ws = (char*)d_ws;

  // workspace layout (simple, non-overlapping; ws is 256 MiB):
  //   0-  4 : xb bf16 x            ->  qb16 (after QKV gemm)
  //   4- 12 : Wt 4x bf16 [n][k]
  //  12- 60 : QKV split-K fp32 partials, 6 x 8MB (q0,q1,k0,k1,v0,v1)
  //  60- 64 : kb16
  //  64- 68 : vt16
  //  68- 84 : Zp (bf16 partials)
  //  84- 85 : Lp
  //  85- 89 : yb
  //  89-105 : o-proj split-K fp32 partials, 2 x 8MB
  u16*   xb   = (u16*)ws;
  u16*   qb16 = (u16*)ws;
  u16*   Wt   = (u16*)(ws + ((size_t)4 << 20));
  float* qkvp = (float*)(ws + ((size_t)12 << 20));   // 6 partials, stride 2M floats
  u16*   kb16 = (u16*)(ws + ((size_t)60 << 20));
  u16*   vt16 = (u16*)(ws + ((size_t)64 << 20));
  u16*   Zp   = (u16*)(ws + ((size_t)68 << 20));
  float* Lp   = (float*)(ws + ((size_t)84 << 20));
  u16*   yb   = (u16*)(ws + ((size_t)85 << 20));
  float* op   = (float*)(ws + ((size_t)89 << 20));   // 2 partials, stride 2M floats
  u16*   Wto  = Wt + (size_t)3 * 1024 * 1024;
  const size_t PSTRIDE = (size_t)2048 * 1024;        // 2M floats = 8MB

  cast_kernel<<<2048, 256, 0, stream>>>(x, xb, 2048 * 1024);
  transcast<<<dim3(16, 16, 4), 256, 0, stream>>>(Wq, Wk, Wv, Wo, Wt);
  // QKV, split-K=2: z = proj*2 + khalf, 768 blocks
  gemm128<<<dim3(8, 16, 6), 256, 0, stream>>>(
      xb, Wt, qkvp, 1024, 1024, (size_t)1024 * 1024, PSTRIDE);
  normrope<<<dim3(8192, 2), 256, 0, stream>>>(
      qkvp + 0 * PSTRIDE, qkvp + 1 * PSTRIDE,
      qkvp + 2 * PSTRIDE, qkvp + 3 * PSTRIDE, qb16, kb16, sqk);
  vtrans<<<dim3(32, 16), 256, 0, stream>>>(qkvp + 4 * PSTRIDE, qkvp + 5 * PSTRIDE, vt16);
  attn_mfma<<<dim3(16, 32, 4), 256, 0, stream>>>(qb16, kb16, vt16, Zp, Lp);
  combine<<<8192, 256, 0, stream>>>(Zp, Lp, yb);
  // o-proj, split-K=2: 256 blocks, then reduce
  gemm128<<<dim3(8, 16, 2), 256, 0, stream>>>(yb, Wto, op, 1024, 1024, 0, PSTRIDE);
  addout<<<2048, 256, 0, stream>>>(op, op + PSTRIDE, out, 2048 * 1024);
}